// Round 3
// baseline (564.485 us; speedup 1.0000x reference)
//
#include <hip/hip_runtime.h>

typedef unsigned short u16;
typedef unsigned int u32;
typedef __attribute__((ext_vector_type(8))) short short8;   // 8 bf16 MFMA frag (4 VGPRs)
typedef __attribute__((ext_vector_type(4))) float f32x4;
typedef __attribute__((ext_vector_type(2))) unsigned int u32x2;
typedef __attribute__((ext_vector_type(4))) unsigned int u32x4;

#define BB 4
#define CC 256
#define NT 4096
#define L2E 1.4426950408889634f

__device__ __forceinline__ float b2f(u16 v) {
    union { u32 u; float f; } c; c.u = ((u32)v) << 16; return c.f;
}
__device__ __forceinline__ u16 f2b(float f) {
    union { float f; u32 u; } c; c.f = f;
    u32 u = c.u;
    return (u16)((u + 0x7fffu + ((u >> 16) & 1u)) >> 16);   // RNE
}

// ---------------------------------------------------------------------------
// K0: prep — Dekker-split W=[Wq;Wk;Wv] (320x256 fp32) into wh/wl bf16 and
// pack biases into one 320-float array. (unchanged from round 2)
// ---------------------------------------------------------------------------
__global__ __launch_bounds__(256) void kprep(
    const float* __restrict__ Wq, const float* __restrict__ Wk,
    const float* __restrict__ Wv, const float* __restrict__ bq,
    const float* __restrict__ bk_, const float* __restrict__ bv,
    u16* __restrict__ wh, u16* __restrict__ wl, float* __restrict__ biasAll)
{
    const int bkx = blockIdx.x;          // 0..19
    const int t = threadIdx.x;
    #pragma unroll
    for (int j = 0; j < 4; ++j) {
        const int idx4 = t + 256 * j;
        const int row  = bkx * 16 + (idx4 >> 6);
        const int col4 = (idx4 & 63) * 4;
        const float* src = row < 32 ? Wq + row * 256
                         : row < 64 ? Wk + (row - 32) * 256
                         :            Wv + (row - 64) * 256;
        f32x4 v = *(const f32x4*)(src + col4);
        u16 h[4], l[4];
        #pragma unroll
        for (int i = 0; i < 4; ++i) {
            h[i] = f2b(v[i]);
            l[i] = f2b(v[i] - b2f(h[i]));
        }
        u32x2 ph, pl;
        ph[0] = (u32)h[0] | ((u32)h[1] << 16); ph[1] = (u32)h[2] | ((u32)h[3] << 16);
        pl[0] = (u32)l[0] | ((u32)l[1] << 16); pl[1] = (u32)l[2] | ((u32)l[3] << 16);
        *(u32x2*)(wh + row * 256 + col4) = ph;
        *(u32x2*)(wl + row * 256 + col4) = pl;
    }
    if (t < 16) {
        const int row = bkx * 16 + t;
        biasAll[row] = row < 32 ? bq[row] : row < 64 ? bk_[row - 32] : bv[row - 64];
    }
}

// ---------------------------------------------------------------------------
// K1 v2: MFMA projections. (unchanged from round 2)
// ---------------------------------------------------------------------------
__global__ __launch_bounds__(256, 1) void kproj(
    const float* __restrict__ x,
    const u16* __restrict__ wh, const u16* __restrict__ wl,
    const float* __restrict__ biasAll,
    u16* __restrict__ qh, u16* __restrict__ ql,
    u16* __restrict__ kh, u16* __restrict__ kl,
    u16* __restrict__ pvw)
{
    __shared__ __align__(16) float lX[256][68];
    __shared__ float lbias[320];
    const int b = blockIdx.y, n0 = blockIdx.x * 64;
    const int t = threadIdx.x;
    const int lane = t & 63, wv = t >> 6;
    const int quad = lane >> 4, l16 = lane & 15;

    {
        const int kX = t >> 3, nn8 = (t & 7) * 8;
        const float* xrow = x + ((size_t)(b * CC + kX)) * NT + n0 + nn8;
        #pragma unroll
        for (int k0 = 0; k0 < 256; k0 += 32) {
            f32x4 xa = *(const f32x4*)(xrow + (size_t)k0 * NT);
            f32x4 xb = *(const f32x4*)(xrow + (size_t)k0 * NT + 4);
            *(f32x4*)&lX[k0 + kX][nn8]     = xa;
            *(f32x4*)&lX[k0 + kX][nn8 + 4] = xb;
        }
        lbias[t] = biasAll[t];
        if (t < 64) lbias[256 + t] = biasAll[256 + t];
    }
    __syncthreads();

    short8 bh[8], bl[8];
    const int coln = wv * 16 + l16;
    #pragma unroll
    for (int s = 0; s < 8; ++s) {
        #pragma unroll
        for (int e = 0; e < 8; ++e) {
            float v = lX[s * 32 + quad * 8 + e][coln];
            u16 h = f2b(v);
            bh[s][e] = (short)h;
            bl[s][e] = (short)f2b(v - b2f(h));
        }
    }

    f32x4 acc[20];
    #pragma unroll
    for (int mt = 0; mt < 20; ++mt) acc[mt] = (f32x4){0.f, 0.f, 0.f, 0.f};

    const u16* whp = wh + l16 * 256 + quad * 8;
    const u16* wlp = wl + l16 * 256 + quad * 8;
    #pragma unroll
    for (int mt = 0; mt < 20; ++mt) {
        #pragma unroll
        for (int s = 0; s < 8; ++s) {
            short8 ah = *(const short8*)(whp + mt * 4096 + s * 32);
            short8 al = *(const short8*)(wlp + mt * 4096 + s * 32);
            acc[mt] = __builtin_amdgcn_mfma_f32_16x16x32_bf16(ah, bh[s], acc[mt], 0, 0, 0);
            acc[mt] = __builtin_amdgcn_mfma_f32_16x16x32_bf16(al, bh[s], acc[mt], 0, 0, 0);
            acc[mt] = __builtin_amdgcn_mfma_f32_16x16x32_bf16(ah, bl[s], acc[mt], 0, 0, 0);
        }
    }

    const int n = n0 + wv * 16 + l16;
    #pragma unroll
    for (int mt = 0; mt < 20; ++mt) {
        u16 hv[4], lv[4];
        #pragma unroll
        for (int i = 0; i < 4; ++i) {
            const int o = mt * 16 + quad * 4 + i;
            const float val = acc[mt][i] + lbias[o];
            hv[i] = f2b(val);
            lv[i] = f2b(val - b2f(hv[i]));
        }
        if (mt < 2) {
            u32x2 ph, pl;
            ph[0] = (u32)hv[0] | ((u32)hv[1] << 16); ph[1] = (u32)hv[2] | ((u32)hv[3] << 16);
            pl[0] = (u32)lv[0] | ((u32)lv[1] << 16); pl[1] = (u32)lv[2] | ((u32)lv[3] << 16);
            const size_t idx = ((size_t)(b * NT + n)) * 32 + mt * 16 + quad * 4;
            *(u32x2*)(qh + idx) = ph;
            *(u32x2*)(ql + idx) = pl;
        } else if (mt < 4) {
            u32x2 ph, pl;
            ph[0] = (u32)hv[0] | ((u32)hv[1] << 16); ph[1] = (u32)hv[2] | ((u32)hv[3] << 16);
            pl[0] = (u32)lv[0] | ((u32)lv[1] << 16); pl[1] = (u32)lv[2] | ((u32)lv[3] << 16);
            const size_t idx = ((size_t)(b * NT + n)) * 32 + (mt - 2) * 16 + quad * 4;
            *(u32x2*)(kh + idx) = ph;
            *(u32x2*)(kl + idx) = pl;
        } else {
            #pragma unroll
            for (int i = 0; i < 4; ++i) {
                const int c = mt * 16 + quad * 4 + i - 64;
                pvw[((size_t)(b * CC + c)) * NT + n] = hv[i];
            }
        }
    }
}

// ---------------------------------------------------------------------------
// K2 v3: energy + masked renormalized softmax -> sa.
// Block = 32 q-rows, 4 waves: wave (rg,ch) = row-group rg*16, ct-half ch*128.
// K tiles (kh+kl, 128B per key row) staged ONCE per block in LDS and shared
// by the 2 waves per ct-half (L2 K-traffic 2GB -> 0.5GB vs v2). Staging is
// reg-staged T14 split (loads issued one step early, ds_write after compute),
// double-buffered, one s_barrier per step. XOR swizzle byte^=((n&7)<<4) on
// BOTH ds_write and ds_read (T2/G4) -> ~2-lane/bank-group on ds_read_b128.
// 2 cts per wave per step; 64 steps per pass; 2 passes (sum, emit).
// ---------------------------------------------------------------------------
__global__ __launch_bounds__(256) void kattn(
    const u16* __restrict__ qh, const u16* __restrict__ ql,
    const u16* __restrict__ kh, const u16* __restrict__ kl,
    const float* __restrict__ valid, float* __restrict__ sa)
{
    __shared__ __align__(16) u16 lK[2 * 4096];   // [buf][4 tiles][16 n][128B] 16KB
    __shared__ float sred[2][2][4][4];           // [rg][ch][quad][i]
    const int b    = blockIdx.y;
    const int t    = threadIdx.x;
    const int lane = t & 63;
    const int wv   = t >> 6;
    const int rg   = wv >> 1, ch = wv & 1;
    const int r0   = blockIdx.x * 32 + rg * 16;
    const int quad = lane >> 4, l16 = lane & 15;

    // q fragments (rows r0..r0+15)
    const size_t abase = ((size_t)(b * NT + r0 + l16)) * 32 + quad * 8;
    const short8 aqh = *(const short8*)(qh + abase);
    const short8 aql = *(const short8*)(ql + abase);
    const float* vb = valid + b * NT + l16;
    const f32x4 zero = {0.f, 0.f, 0.f, 0.f};
    u16* lKf = &lK[0];

    // staging roles: granule g (16B): tile=g>>7, w=g&127, n=w>>3, c16=w&7
    // tile tl covers ct = (tl>>1)*128 + (tl&1) + 2*s ; c16<4 -> kh, else kl
    int g1 = t, g2 = t + 256;
    const int tl1 = g1 >> 7, n1 = (g1 >> 3) & 15, c161 = g1 & 7;
    const int tl2 = g2 >> 7, n2 = (g2 >> 3) & 15, c162 = g2 & 7;
    const int cb1 = (tl1 >> 1) * 128 + (tl1 & 1);
    const int cb2 = (tl2 >> 1) * 128 + (tl2 & 1);
    const u16* src1 = (c161 < 4 ? kh : kl) + (size_t)b * NT * 32 + (size_t)n1 * 32 + (c161 & 3) * 8;
    const u16* src2 = (c162 < 4 ? kh : kl) + (size_t)b * NT * 32 + (size_t)n2 * 32 + (c162 & 3) * 8;
    const int ldso1 = tl1 * 1024 + n1 * 64 + ((((c161 * 16) ^ ((n1 & 7) << 4))) >> 1);
    const int ldso2 = tl2 * 1024 + n2 * 64 + ((((c162 * 16) ^ ((n2 & 7) << 4))) >> 1);

    // fragment read offsets (u16 units within one buffer)
    const int base0 = (2 * ch) * 1024;
    const int base1 = base0 + 1024;
    const int khoff = l16 * 64 + (((quad * 16) ^ ((l16 & 7) << 4)) >> 1);
    const int kloff = l16 * 64 + (((64 + quad * 16) ^ ((l16 & 7) << 4)) >> 1);

#define KATTN_PROLOGUE()                                                       \
    {                                                                          \
        u32x4 r1 = *(const u32x4*)(src1 + (size_t)cb1 * 512);                  \
        u32x4 r2 = *(const u32x4*)(src2 + (size_t)cb2 * 512);                  \
        asm volatile("s_waitcnt vmcnt(0)" ::: "memory");                       \
        __builtin_amdgcn_sched_barrier(0);                                     \
        *(u32x4*)(lKf + ldso1) = r1;                                           \
        *(u32x4*)(lKf + ldso2) = r2;                                           \
        asm volatile("s_waitcnt lgkmcnt(0)" ::: "memory");                     \
        __builtin_amdgcn_sched_barrier(0);                                     \
        __builtin_amdgcn_s_barrier();                                          \
        __builtin_amdgcn_sched_barrier(0);                                     \
    }

#define KATTN_STEP_TAIL(S)                                                     \
    if ((S) + 1 < 64) {                                                        \
        asm volatile("s_waitcnt vmcnt(0)" ::: "memory");                       \
        __builtin_amdgcn_sched_barrier(0);                                     \
        *(u32x4*)(lKf + (((S) + 1) & 1) * 4096 + ldso1) = r1;                  \
        *(u32x4*)(lKf + (((S) + 1) & 1) * 4096 + ldso2) = r2;                  \
    }                                                                          \
    asm volatile("s_waitcnt lgkmcnt(0)" ::: "memory");                         \
    __builtin_amdgcn_sched_barrier(0);                                         \
    __builtin_amdgcn_s_barrier();                                              \
    __builtin_amdgcn_sched_barrier(0);

    // ---------------- pass 1: row sums ----------------
    float sacc[4] = {0.f, 0.f, 0.f, 0.f};
    KATTN_PROLOGUE();
    for (int s = 0; s < 64; ++s) {
        u32x4 r1, r2;
        if (s + 1 < 64) {   // early-issue loads for step s+1
            r1 = *(const u32x4*)(src1 + (size_t)(cb1 + 2 * (s + 1)) * 512);
            r2 = *(const u32x4*)(src2 + (size_t)(cb2 + 2 * (s + 1)) * 512);
        }
        const u16* lbuf = lKf + (s & 1) * 4096;
        short8 bh0 = *(const short8*)(lbuf + base0 + khoff);
        short8 bl0 = *(const short8*)(lbuf + base0 + kloff);
        short8 bh1 = *(const short8*)(lbuf + base1 + khoff);
        short8 bl1 = *(const short8*)(lbuf + base1 + kloff);
        const int ct0 = ch * 128 + 2 * s;
        const float v0 = vb[ct0 * 16], v1 = vb[(ct0 + 1) * 16];
        f32x4 d0 = __builtin_amdgcn_mfma_f32_16x16x32_bf16(aqh, bh0, zero, 0, 0, 0);
        d0 = __builtin_amdgcn_mfma_f32_16x16x32_bf16(aql, bh0, d0, 0, 0, 0);
        d0 = __builtin_amdgcn_mfma_f32_16x16x32_bf16(aqh, bl0, d0, 0, 0, 0);
        f32x4 d1 = __builtin_amdgcn_mfma_f32_16x16x32_bf16(aqh, bh1, zero, 0, 0, 0);
        d1 = __builtin_amdgcn_mfma_f32_16x16x32_bf16(aql, bh1, d1, 0, 0, 0);
        d1 = __builtin_amdgcn_mfma_f32_16x16x32_bf16(aqh, bl1, d1, 0, 0, 0);
        #pragma unroll
        for (int i = 0; i < 4; ++i)
            sacc[i] += v0 * exp2f(fminf(d0[i], 60.f) * L2E)
                     + v1 * exp2f(fminf(d1[i], 60.f) * L2E);
        KATTN_STEP_TAIL(s)
    }

    // reduce over l16, then across ct-half waves
    #pragma unroll
    for (int i = 0; i < 4; ++i) {
        #pragma unroll
        for (int off = 1; off < 16; off <<= 1)
            sacc[i] += __shfl_xor(sacc[i], off, 64);
    }
    if (l16 == 0) {
        #pragma unroll
        for (int i = 0; i < 4; ++i) sred[rg][ch][quad][i] = sacc[i];
    }
    __syncthreads();
    float inv[4];
    #pragma unroll
    for (int i = 0; i < 4; ++i)
        inv[i] = 1.0f / (sred[rg][0][quad][i] + sred[rg][1][quad][i]);
    __syncthreads();   // protect lK reuse by pass 2

    // ---------------- pass 2: emit ----------------
    float* sabase = sa + ((size_t)(b * NT + r0 + quad * 4)) * NT + l16;
    KATTN_PROLOGUE();
    for (int s = 0; s < 64; ++s) {
        u32x4 r1, r2;
        if (s + 1 < 64) {
            r1 = *(const u32x4*)(src1 + (size_t)(cb1 + 2 * (s + 1)) * 512);
            r2 = *(const u32x4*)(src2 + (size_t)(cb2 + 2 * (s + 1)) * 512);
        }
        const u16* lbuf = lKf + (s & 1) * 4096;
        short8 bh0 = *(const short8*)(lbuf + base0 + khoff);
        short8 bl0 = *(const short8*)(lbuf + base0 + kloff);
        short8 bh1 = *(const short8*)(lbuf + base1 + khoff);
        short8 bl1 = *(const short8*)(lbuf + base1 + kloff);
        const int ct0 = ch * 128 + 2 * s;
        const float v0 = vb[ct0 * 16], v1 = vb[(ct0 + 1) * 16];
        f32x4 d0 = __builtin_amdgcn_mfma_f32_16x16x32_bf16(aqh, bh0, zero, 0, 0, 0);
        d0 = __builtin_amdgcn_mfma_f32_16x16x32_bf16(aql, bh0, d0, 0, 0, 0);
        d0 = __builtin_amdgcn_mfma_f32_16x16x32_bf16(aqh, bl0, d0, 0, 0, 0);
        f32x4 d1 = __builtin_amdgcn_mfma_f32_16x16x32_bf16(aqh, bh1, zero, 0, 0, 0);
        d1 = __builtin_amdgcn_mfma_f32_16x16x32_bf16(aql, bh1, d1, 0, 0, 0);
        d1 = __builtin_amdgcn_mfma_f32_16x16x32_bf16(aqh, bl1, d1, 0, 0, 0);
        #pragma unroll
        for (int i = 0; i < 4; ++i) {
            sabase[(size_t)i * NT + ct0 * 16]
                = v0 * exp2f(fminf(d0[i], 60.f) * L2E) * inv[i];
            sabase[(size_t)i * NT + (ct0 + 1) * 16]
                = v1 * exp2f(fminf(d1[i], 60.f) * L2E) * inv[i];
        }
        KATTN_STEP_TAIL(s)
    }
#undef KATTN_PROLOGUE
#undef KATTN_STEP_TAIL
}

// ---------------------------------------------------------------------------
// K3: out[b,c,m] = gamma * sum_n pv[c,n]*sa[m,n] + x[b,c,m]. (unchanged)
// ---------------------------------------------------------------------------
#define KOUT_BODY(CUR, T, NXA, NXB, FTA, FTB)                                  \
  {                                                                            \
    if ((T) + 2 < 32) {                                                        \
      FTA = *(const f32x4*)(sap + (size_t)((T) + 2) * 128);                    \
      FTB = *(const f32x4*)(sap + (size_t)((T) + 2) * 128 + 4);                \
    }                                                                          \
    if ((T) + 1 < 32) {                                                        \
      u32 w0 = (u32)f2b(NXA[0]) | ((u32)f2b(NXA[1]) << 16);                    \
      u32 w1 = (u32)f2b(NXA[2]) | ((u32)f2b(NXA[3]) << 16);                    \
      u32 w2 = (u32)f2b(NXB[0]) | ((u32)f2b(NXB[1]) << 16);                    \
      u32 w3 = (u32)f2b(NXB[2]) | ((u32)f2b(NXB[3]) << 16);                    \
      u32x4 pk = {w0, w1, w2, w3};                                             \
      *(u32x4*)(lbw + ((((T) + 1) & 1) * 8192)) = pk;                          \
    }                                                                          \
    const char* lb = lbr + (CUR) * 8192;                                       \
    _Pragma("unroll")                                                          \
    for (int kk = 0; kk < 128; kk += 32) {                                     \
      short8 a0 = *(const short8*)(a0p + (size_t)(T) * 128 + kk);              \
      short8 a1 = *(const short8*)(a1p + (size_t)(T) * 128 + kk);              \
      const int kby = (((kk + quad * 8) * 2) ^ swz);                           \
      short8 b0 = *(const short8*)(lb + l16 * 256 + kby);                      \
      short8 b1 = *(const short8*)(lb + (16 + l16) * 256 + kby);               \
      acc00 = __builtin_amdgcn_mfma_f32_16x16x32_bf16(a0, b0, acc00, 0, 0, 0); \
      acc01 = __builtin_amdgcn_mfma_f32_16x16x32_bf16(a0, b1, acc01, 0, 0, 0); \
      acc10 = __builtin_amdgcn_mfma_f32_16x16x32_bf16(a1, b0, acc10, 0, 0, 0); \
      acc11 = __builtin_amdgcn_mfma_f32_16x16x32_bf16(a1, b1, acc11, 0, 0, 0); \
    }                                                                          \
    asm volatile("s_waitcnt lgkmcnt(0)" ::: "memory");                         \
    __builtin_amdgcn_sched_barrier(0);                                         \
    __builtin_amdgcn_s_barrier();                                              \
    __builtin_amdgcn_sched_barrier(0);                                         \
  }

__global__ __launch_bounds__(512) void kout(
    const u16* __restrict__ pvw, const float* __restrict__ sa,
    const float* __restrict__ x, const float* __restrict__ gamma,
    float* __restrict__ outp)
{
    __shared__ __align__(16) u16 lB[2][32][128];
    const int b    = blockIdx.y;
    const int m0   = blockIdx.x * 32;
    const int t    = threadIdx.x;
    const int lane = t & 63;
    const int wv   = t >> 6;
    const int c0   = wv * 32;
    const int quad = lane >> 4, l16 = lane & 15;
    const int swz  = (l16 & 7) << 4;

    const u16* a0p = pvw + ((size_t)(b * CC + c0 + l16)) * NT + quad * 8;
    const u16* a1p = a0p + (size_t)16 * NT;
    const int sm = t >> 4, sk = (t & 15) * 8;
    const float* sap = sa + ((size_t)(b * NT + m0 + sm)) * NT + sk;
    char* lbw = ((char*)&lB[0][0][0]) + sm * 256 + ((sk * 2) ^ ((sm & 7) << 4));
    const char* lbr = (const char*)&lB[0][0][0];

    f32x4 acc00 = {0,0,0,0}, acc01 = {0,0,0,0}, acc10 = {0,0,0,0}, acc11 = {0,0,0,0};

    f32x4 pA = *(const f32x4*)(sap);
    f32x4 pB = *(const f32x4*)(sap + 4);
    f32x4 nA = *(const f32x4*)(sap + 128);
    f32x4 nB = *(const f32x4*)(sap + 132);
    {
        u32 w0 = (u32)f2b(pA[0]) | ((u32)f2b(pA[1]) << 16);
        u32 w1 = (u32)f2b(pA[2]) | ((u32)f2b(pA[3]) << 16);
        u32 w2 = (u32)f2b(pB[0]) | ((u32)f2b(pB[1]) << 16);
        u32 w3 = (u32)f2b(pB[2]) | ((u32)f2b(pB[3]) << 16);
        u32x4 pk = {w0, w1, w2, w3};
        *(u32x4*)(lbw) = pk;
    }
    asm volatile("s_waitcnt lgkmcnt(0)" ::: "memory");
    __builtin_amdgcn_sched_barrier(0);
    __builtin_amdgcn_s_barrier();
    __builtin_amdgcn_sched_barrier(0);

    f32x4 fA, fB;
    for (int tt = 0; tt < 32; tt += 2) {
        KOUT_BODY(0, tt,     nA, nB, fA, fB)
        KOUT_BODY(1, tt + 1, fA, fB, nA, nB)
    }

    const float g = gamma[0];
    #pragma unroll
    for (int ai = 0; ai < 2; ++ai) {
        #pragma unroll
        for (int bi = 0; bi < 2; ++bi) {
            f32x4 acc = (ai == 0) ? ((bi == 0) ? acc00 : acc01)
                                  : ((bi == 0) ? acc10 : acc11);
            #pragma unroll
            for (int i = 0; i < 4; ++i) {
                const int c = c0 + ai * 16 + quad * 4 + i;
                const int m = m0 + bi * 16 + l16;
                const size_t idx = ((size_t)(b * CC + c)) * NT + m;
                outp[idx] = g * acc[i] + x[idx];
            }
        }
    }
}

extern "C" void kernel_launch(void* const* d_in, const int* in_sizes, int n_in,
                              void* d_out, int out_size, void* d_ws, size_t ws_size,
                              hipStream_t stream)
{
    const float* x     = (const float*)d_in[0];
    const float* valid = (const float*)d_in[1];
    const float* Wq    = (const float*)d_in[2];
    const float* bq    = (const float*)d_in[3];
    const float* Wk    = (const float*)d_in[4];
    const float* bk    = (const float*)d_in[5];
    const float* Wv    = (const float*)d_in[6];
    const float* bv    = (const float*)d_in[7];
    const float* gamma = (const float*)d_in[8];

    float* outp = (float*)d_out;
    float* sa   = outp + (size_t)BB * CC * NT;      // output chunk 1 [B][N][N] fp32

    u16* qh  = (u16*)d_ws;                          // [B][N][32] bf16, 1 MB each
    u16* ql  = qh + (size_t)BB * NT * 32;
    u16* kh  = ql + (size_t)BB * NT * 32;
    u16* kl  = kh + (size_t)BB * NT * 32;
    u16* pvw = kl + (size_t)BB * NT * 32;           // [B][C][N] bf16, 8 MB
    u16* wh  = pvw + (size_t)BB * CC * NT;          // 320x256 bf16, 160 KB
    u16* wl  = wh + 320 * 256;
    float* biasAll = (float*)(wl + 320 * 256);      // 320 fp32

    kprep<<<dim3(20), 256, 0, stream>>>(Wq, Wk, Wv, bq, bk, bv, wh, wl, biasAll);
    kproj<<<dim3(64, BB), 256, 0, stream>>>(x, wh, wl, biasAll,
                                            qh, ql, kh, kl, pvw);
    kattn<<<dim3(128, BB), 256, 0, stream>>>(qh, ql, kh, kl, valid, sa);
    kout<<<dim3(128, BB), 512, 0, stream>>>(pvw, sa, x, gamma, outp);
}

// Round 4
// 531.375 us; speedup vs baseline: 1.0623x; 1.0623x over previous
//
#include <hip/hip_runtime.h>

typedef unsigned short u16;
typedef unsigned int u32;
typedef __attribute__((ext_vector_type(8))) short short8;   // 8 bf16 MFMA frag (4 VGPRs)
typedef __attribute__((ext_vector_type(4))) float f32x4;
typedef __attribute__((ext_vector_type(2))) unsigned int u32x2;
typedef __attribute__((ext_vector_type(4))) unsigned int u32x4;

#define BB 4
#define CC 256
#define NT 4096
#define L2E 1.4426950408889634f

__device__ __forceinline__ float b2f(u16 v) {
    union { u32 u; float f; } c; c.u = ((u32)v) << 16; return c.f;
}
__device__ __forceinline__ u16 f2b(float f) {
    union { float f; u32 u; } c; c.f = f;
    u32 u = c.u;
    return (u16)((u + 0x7fffu + ((u >> 16) & 1u)) >> 16);   // RNE
}

// ---------------------------------------------------------------------------
// K1: fused projections (fp32 in). Y = [Wq;Wk;Wv](320x256) @ x(256x4096) per b.
// fp32 VALU GEMM, LDS tiles, 4x4 reg tiling. Emits bf16 MFMA-layout outputs:
//   qh/ql [b][n][32] (Dekker split q=qh+ql), kh/kl [b][m][32], pvw [b][c][n].
// (R1 version — the MFMA rewrite measured neutral, reverted.)
// ---------------------------------------------------------------------------
__global__ __launch_bounds__(256) void kproj(
    const float* __restrict__ x,
    const float* __restrict__ Wq, const float* __restrict__ bq,
    const float* __restrict__ Wk, const float* __restrict__ bk,
    const float* __restrict__ Wv, const float* __restrict__ bv,
    u16* __restrict__ qh, u16* __restrict__ ql,
    u16* __restrict__ kh, u16* __restrict__ kl,
    u16* __restrict__ pvw)
{
    __shared__ __align__(16) float lA[32][68];   // [k][row]
    __shared__ __align__(16) float lX[32][68];   // [k][col]
    const int mt = blockIdx.x, nt = blockIdx.y, b = blockIdx.z;
    const int t = threadIdx.x;
    const int tx = t & 15, ty = t >> 4;
    const int n0 = nt * 64;

    float acc[4][4];
    #pragma unroll
    for (int i = 0; i < 4; ++i)
        #pragma unroll
        for (int j = 0; j < 4; ++j) acc[i][j] = 0.f;

    const int rA = t >> 2, kqA = (t & 3) * 8;
    const int rgA = mt * 64 + rA;
    const float* wrow;
    if (rgA < 32)      wrow = Wq + rgA * 256;
    else if (rgA < 64) wrow = Wk + (rgA - 32) * 256;
    else               wrow = Wv + (rgA - 64) * 256;
    const int kX = t >> 3, nn8 = (t & 7) * 8;
    const float* xrow = x + ((size_t)(b * CC + kX)) * NT + n0 + nn8;

    for (int k0 = 0; k0 < 256; k0 += 32) {
        f32x4 wa = *(const f32x4*)(wrow + k0 + kqA);
        f32x4 wb = *(const f32x4*)(wrow + k0 + kqA + 4);
        f32x4 xa = *(const f32x4*)(xrow + (size_t)k0 * NT);
        f32x4 xb = *(const f32x4*)(xrow + (size_t)k0 * NT + 4);
        __syncthreads();
        #pragma unroll
        for (int j = 0; j < 4; ++j) {
            lA[kqA + j    ][rA] = wa[j];
            lA[kqA + j + 4][rA] = wb[j];
        }
        *(f32x4*)&lX[kX][nn8]     = xa;
        *(f32x4*)&lX[kX][nn8 + 4] = xb;
        __syncthreads();
        #pragma unroll
        for (int k = 0; k < 32; ++k) {
            f32x4 av  = *(const f32x4*)&lA[k][ty * 4];
            f32x4 xvv = *(const f32x4*)&lX[k][tx * 4];
            #pragma unroll
            for (int i = 0; i < 4; ++i)
                #pragma unroll
                for (int j = 0; j < 4; ++j)
                    acc[i][j] = fmaf(av[i], xvv[j], acc[i][j]);
        }
    }

    #pragma unroll
    for (int i = 0; i < 4; ++i) {
        const int rg = mt * 64 + ty * 4 + i;
        float bias;
        if (rg < 32)      bias = bq[rg];
        else if (rg < 64) bias = bk[rg - 32];
        else              bias = bv[rg - 64];
        #pragma unroll
        for (int j = 0; j < 4; ++j) {
            const int n = n0 + tx * 4 + j;
            const float val = acc[i][j] + bias;
            const u16 h = f2b(val);
            const u16 l = f2b(val - b2f(h));
            if (rg < 32) {
                const size_t idx = ((size_t)(b * NT + n)) * 32 + rg;
                qh[idx] = h; ql[idx] = l;
            } else if (rg < 64) {
                const size_t idx = ((size_t)(b * NT + n)) * 32 + (rg - 32);
                kh[idx] = h; kl[idx] = l;
            } else {
                pvw[((size_t)b * CC + (rg - 64)) * NT + n] = f2b(val);
            }
        }
    }
}

// ---------------------------------------------------------------------------
// K2 (fused): sa + out in one kernel. Block = 512 thr (8 waves), owns 32
// q-rows (m0..m0+31) and all 4096 k-cols.
//
// SWAPPED QK^T: mfma(A=K, B=Q) -> D[row = k-col = quad*4+i][col = q-row = l16]
// so each lane holds f32x4 ALONG k for one q-row:
//   - sa store becomes a coalesced dwordx4 (v2 had 4 scattered 64B stores)
//   - bf16 pack writes directly into the [m][k] B-frag layout PV needs
//
// Phase 1: wave (rg,cq) sums v*exp over cts cq*64..+63 for rows rg*16+l16;
//          shfl over quads + LDS reduce over cq -> inv[row] (1 reg/lane).
// Phase 2: per 64-col k-step: wave (rg,cq) computes 16x16 sa tile
//          (ct = s*4+cq), stores sa fp32, packs bf16 -> swizzled LDS
//          (byte ^= ((m&7)<<4), both sides), ONE raw s_barrier (lgkmcnt only
//          — pv/K prefetch vmcnt stays in flight, T4), then kout-style PV:
//          each wave c-quadrant wv*32, 8 MFMAs vs staged tile. Dbuf LDS.
// kout's 268 MB sa HBM read is eliminated entirely.
// ---------------------------------------------------------------------------
#define FSTEP(S, CBH, CBL, CV4, NBH, NBL, NV4)                                 \
  {                                                                            \
    const int s_ = (S);                                                        \
    short8 pa00 = *(const short8*)(pva + (size_t)s_ * 64);                     \
    short8 pa01 = *(const short8*)(pva + (size_t)s_ * 64 + 32);                \
    short8 pa10 = *(const short8*)(pva + (size_t)16 * NT + (size_t)s_ * 64);   \
    short8 pa11 = *(const short8*)(pva + (size_t)16 * NT + (size_t)s_ * 64 + 32);\
    if (s_ + 1 < 64) {                                                         \
      const int ct_ = (s_ + 1) * 4 + cq;                                       \
      NBH = *(const short8*)(kh + kbase + (size_t)ct_ * 512);                  \
      NBL = *(const short8*)(kl + kbase + (size_t)ct_ * 512);                  \
      NV4 = *(const f32x4*)(vbase + ct_ * 16 + quad * 4);                      \
    }                                                                          \
    f32x4 d = __builtin_amdgcn_mfma_f32_16x16x32_bf16(CBH, aqh, zero, 0, 0, 0);\
    d = __builtin_amdgcn_mfma_f32_16x16x32_bf16(CBH, aql, d, 0, 0, 0);         \
    d = __builtin_amdgcn_mfma_f32_16x16x32_bf16(CBL, aqh, d, 0, 0, 0);         \
    f32x4 val;                                                                 \
    _Pragma("unroll")                                                          \
    for (int i = 0; i < 4; ++i)                                                \
      val[i] = CV4[i] * exp2f(fminf(d[i], 60.f) * L2E) * inv;                  \
    *(f32x4*)(sap + (size_t)s_ * 64 + cq * 16 + quad * 4) = val;               \
    u32x2 pk;                                                                  \
    pk[0] = (u32)f2b(val[0]) | ((u32)f2b(val[1]) << 16);                       \
    pk[1] = (u32)f2b(val[2]) | ((u32)f2b(val[3]) << 16);                       \
    *(u32x2*)(lwp + (s_ & 1) * 4096) = pk;                                     \
    asm volatile("s_waitcnt lgkmcnt(0)" ::: "memory");                         \
    __builtin_amdgcn_sched_barrier(0);                                         \
    __builtin_amdgcn_s_barrier();                                              \
    __builtin_amdgcn_sched_barrier(0);                                         \
    const char* lb_ = lrp + (s_ & 1) * 4096;                                   \
    _Pragma("unroll")                                                          \
    for (int half = 0; half < 2; ++half) {                                     \
      const int kby_ = ((half * 64 + quad * 16) ^ swz);                        \
      short8 b0 = *(const short8*)(lb_ + l16 * 128 + kby_);                    \
      short8 b1 = *(const short8*)(lb_ + (16 + l16) * 128 + kby_);             \
      short8 a0 = half ? pa01 : pa00;                                          \
      short8 a1 = half ? pa11 : pa10;                                          \
      acc00 = __builtin_amdgcn_mfma_f32_16x16x32_bf16(a0, b0, acc00, 0, 0, 0); \
      acc01 = __builtin_amdgcn_mfma_f32_16x16x32_bf16(a0, b1, acc01, 0, 0, 0); \
      acc10 = __builtin_amdgcn_mfma_f32_16x16x32_bf16(a1, b0, acc10, 0, 0, 0); \
      acc11 = __builtin_amdgcn_mfma_f32_16x16x32_bf16(a1, b1, acc11, 0, 0, 0); \
    }                                                                          \
  }

__global__ __launch_bounds__(512, 4) void ksaout(
    const u16* __restrict__ qh, const u16* __restrict__ ql,
    const u16* __restrict__ kh, const u16* __restrict__ kl,
    const float* __restrict__ valid, const u16* __restrict__ pvw,
    const float* __restrict__ x, const float* __restrict__ gamma,
    float* __restrict__ sa, float* __restrict__ outp)
{
    __shared__ __align__(16) u16 lB[2][32][64];   // [buf][m][k] swizzled, 8 KB
    __shared__ float sred[2][4][16];              // [rg][cq][row]
    const int b    = blockIdx.y;
    const int m0   = blockIdx.x * 32;
    const int t    = threadIdx.x;
    const int lane = t & 63;
    const int wv   = t >> 6;
    const int quad = lane >> 4, l16 = lane & 15;
    const int rg   = wv >> 2, cq = wv & 3;
    const int swz  = (l16 & 7) << 4;

    // Q fragments for this wave's 16 q-rows (B-operand of swapped QK^T)
    const size_t qbase = ((size_t)(b * NT + m0 + rg * 16 + l16)) * 32 + quad * 8;
    const short8 aqh = *(const short8*)(qh + qbase);
    const short8 aql = *(const short8*)(ql + qbase);
    // K fragment base (A-operand): key row ct*16+l16, channel chunk quad*8
    const size_t kbase = (size_t)b * NT * 32 + (size_t)l16 * 32 + quad * 8;
    const float* vbase = valid + (size_t)b * NT;
    const f32x4 zero = {0.f, 0.f, 0.f, 0.f};

    // ---------------- phase 1: row sums ----------------
    float sacc = 0.f;
    {
        short8 nbh = *(const short8*)(kh + kbase + (size_t)(cq * 64) * 512);
        short8 nbl = *(const short8*)(kl + kbase + (size_t)(cq * 64) * 512);
        f32x4  nv4 = *(const f32x4*)(vbase + (cq * 64) * 16 + quad * 4);
        for (int s = 0; s < 64; ++s) {
            short8 bh = nbh, bl = nbl;
            f32x4 v4 = nv4;
            if (s + 1 < 64) {
                const int ct = cq * 64 + s + 1;
                nbh = *(const short8*)(kh + kbase + (size_t)ct * 512);
                nbl = *(const short8*)(kl + kbase + (size_t)ct * 512);
                nv4 = *(const f32x4*)(vbase + ct * 16 + quad * 4);
            }
            f32x4 d = __builtin_amdgcn_mfma_f32_16x16x32_bf16(bh, aqh, zero, 0, 0, 0);
            d = __builtin_amdgcn_mfma_f32_16x16x32_bf16(bh, aql, d, 0, 0, 0);
            d = __builtin_amdgcn_mfma_f32_16x16x32_bf16(bl, aqh, d, 0, 0, 0);
            #pragma unroll
            for (int i = 0; i < 4; ++i)
                sacc += v4[i] * exp2f(fminf(d[i], 60.f) * L2E);
        }
    }
    sacc += __shfl_xor(sacc, 16, 64);
    sacc += __shfl_xor(sacc, 32, 64);
    if (lane < 16) sred[rg][cq][l16] = sacc;
    __syncthreads();
    const float inv = 1.0f / (sred[rg][0][l16] + sred[rg][1][l16] +
                              sred[rg][2][l16] + sred[rg][3][l16]);

    // ---------------- phase 2: emit sa + PV accumulate ----------------
    // pv A-frags: out rows c = wv*32 + {l16, 16+l16}
    const u16* pva = pvw + ((size_t)(b * CC + wv * 32 + l16)) * NT + quad * 8;
    float* sap = sa + ((size_t)(b * NT + m0 + rg * 16 + l16)) * NT;
    char* lwp = (char*)&lB[0][0][0] + (rg * 16 + l16) * 128
              + ((cq * 32 + quad * 8) ^ swz);
    const char* lrp = (const char*)&lB[0][0][0];

    f32x4 acc00 = {0,0,0,0}, acc01 = {0,0,0,0}, acc10 = {0,0,0,0}, acc11 = {0,0,0,0};

    short8 cbh = *(const short8*)(kh + kbase + (size_t)cq * 512);
    short8 cbl = *(const short8*)(kl + kbase + (size_t)cq * 512);
    f32x4  cv4 = *(const f32x4*)(vbase + cq * 16 + quad * 4);
    short8 nbh, nbl; f32x4 nv4;

    for (int s = 0; s < 64; s += 2) {
        FSTEP(s,     cbh, cbl, cv4, nbh, nbl, nv4)
        FSTEP(s + 1, nbh, nbl, nv4, cbh, cbl, cv4)
    }

    // epilogue: D row = c (A rows), col = m (B cols) — same as old kout
    const float g = gamma[0];
    #pragma unroll
    for (int ai = 0; ai < 2; ++ai) {
        #pragma unroll
        for (int bi = 0; bi < 2; ++bi) {
            f32x4 acc = (ai == 0) ? ((bi == 0) ? acc00 : acc01)
                                  : ((bi == 0) ? acc10 : acc11);
            #pragma unroll
            for (int i = 0; i < 4; ++i) {
                const int c = wv * 32 + ai * 16 + quad * 4 + i;
                const int m = m0 + bi * 16 + l16;
                const size_t idx = ((size_t)(b * CC + c)) * NT + m;
                outp[idx] = g * acc[i] + x[idx];
            }
        }
    }
}

extern "C" void kernel_launch(void* const* d_in, const int* in_sizes, int n_in,
                              void* d_out, int out_size, void* d_ws, size_t ws_size,
                              hipStream_t stream)
{
    const float* x     = (const float*)d_in[0];
    const float* valid = (const float*)d_in[1];
    const float* Wq    = (const float*)d_in[2];
    const float* bq    = (const float*)d_in[3];
    const float* Wk    = (const float*)d_in[4];
    const float* bk    = (const float*)d_in[5];
    const float* Wv    = (const float*)d_in[6];
    const float* bv    = (const float*)d_in[7];
    const float* gamma = (const float*)d_in[8];

    float* outp = (float*)d_out;
    float* sa   = outp + (size_t)BB * CC * NT;      // output chunk 1 [B][N][N] fp32

    u16* qh  = (u16*)d_ws;                          // [B][N][32] bf16, 1 MB each
    u16* ql  = qh + (size_t)BB * NT * 32;
    u16* kh  = ql + (size_t)BB * NT * 32;
    u16* kl  = kh + (size_t)BB * NT * 32;
    u16* pvw = kl + (size_t)BB * NT * 32;           // [B][C][N] bf16, 8 MB

    kproj<<<dim3(5, 64, BB), 256, 0, stream>>>(x, Wq, bq, Wk, bk, Wv, bv,
                                               qh, ql, kh, kl, pvw);
    ksaout<<<dim3(128, BB), 512, 0, stream>>>(qh, ql, kh, kl, valid, pvw,
                                              x, gamma, sa, outp);
}

// Round 5
// 522.833 us; speedup vs baseline: 1.0797x; 1.0163x over previous
//
#include <hip/hip_runtime.h>

typedef unsigned short u16;
typedef unsigned int u32;
typedef __attribute__((ext_vector_type(8))) short short8;   // 8 bf16 MFMA frag (4 VGPRs)
typedef __attribute__((ext_vector_type(4))) float f32x4;
typedef __attribute__((ext_vector_type(2))) unsigned int u32x2;
typedef __attribute__((ext_vector_type(4))) unsigned int u32x4;

#define BB 4
#define CC 256
#define NT 4096
#define L2E 1.4426950408889634f

__device__ __forceinline__ float b2f(u16 v) {
    union { u32 u; float f; } c; c.u = ((u32)v) << 16; return c.f;
}
__device__ __forceinline__ u16 f2b(float f) {
    union { float f; u32 u; } c; c.f = f;
    u32 u = c.u;
    return (u16)((u + 0x7fffu + ((u >> 16) & 1u)) >> 16);   // RNE
}

// ---------------------------------------------------------------------------
// K1: fused projections (fp32 in). Y = [Wq;Wk;Wv](320x256) @ x(256x4096) per b.
// fp32 VALU GEMM, LDS tiles, 4x4 reg tiling. (unchanged — R1 version)
// ---------------------------------------------------------------------------
__global__ __launch_bounds__(256) void kproj(
    const float* __restrict__ x,
    const float* __restrict__ Wq, const float* __restrict__ bq,
    const float* __restrict__ Wk, const float* __restrict__ bk,
    const float* __restrict__ Wv, const float* __restrict__ bv,
    u16* __restrict__ qh, u16* __restrict__ ql,
    u16* __restrict__ kh, u16* __restrict__ kl,
    u16* __restrict__ pvw)
{
    __shared__ __align__(16) float lA[32][68];   // [k][row]
    __shared__ __align__(16) float lX[32][68];   // [k][col]
    const int mt = blockIdx.x, nt = blockIdx.y, b = blockIdx.z;
    const int t = threadIdx.x;
    const int tx = t & 15, ty = t >> 4;
    const int n0 = nt * 64;

    float acc[4][4];
    #pragma unroll
    for (int i = 0; i < 4; ++i)
        #pragma unroll
        for (int j = 0; j < 4; ++j) acc[i][j] = 0.f;

    const int rA = t >> 2, kqA = (t & 3) * 8;
    const int rgA = mt * 64 + rA;
    const float* wrow;
    if (rgA < 32)      wrow = Wq + rgA * 256;
    else if (rgA < 64) wrow = Wk + (rgA - 32) * 256;
    else               wrow = Wv + (rgA - 64) * 256;
    const int kX = t >> 3, nn8 = (t & 7) * 8;
    const float* xrow = x + ((size_t)(b * CC + kX)) * NT + n0 + nn8;

    for (int k0 = 0; k0 < 256; k0 += 32) {
        f32x4 wa = *(const f32x4*)(wrow + k0 + kqA);
        f32x4 wb = *(const f32x4*)(wrow + k0 + kqA + 4);
        f32x4 xa = *(const f32x4*)(xrow + (size_t)k0 * NT);
        f32x4 xb = *(const f32x4*)(xrow + (size_t)k0 * NT + 4);
        __syncthreads();
        #pragma unroll
        for (int j = 0; j < 4; ++j) {
            lA[kqA + j    ][rA] = wa[j];
            lA[kqA + j + 4][rA] = wb[j];
        }
        *(f32x4*)&lX[kX][nn8]     = xa;
        *(f32x4*)&lX[kX][nn8 + 4] = xb;
        __syncthreads();
        #pragma unroll
        for (int k = 0; k < 32; ++k) {
            f32x4 av  = *(const f32x4*)&lA[k][ty * 4];
            f32x4 xvv = *(const f32x4*)&lX[k][tx * 4];
            #pragma unroll
            for (int i = 0; i < 4; ++i)
                #pragma unroll
                for (int j = 0; j < 4; ++j)
                    acc[i][j] = fmaf(av[i], xvv[j], acc[i][j]);
        }
    }

    #pragma unroll
    for (int i = 0; i < 4; ++i) {
        const int rg = mt * 64 + ty * 4 + i;
        float bias;
        if (rg < 32)      bias = bq[rg];
        else if (rg < 64) bias = bk[rg - 32];
        else              bias = bv[rg - 64];
        #pragma unroll
        for (int j = 0; j < 4; ++j) {
            const int n = n0 + tx * 4 + j;
            const float val = acc[i][j] + bias;
            const u16 h = f2b(val);
            const u16 l = f2b(val - b2f(h));
            if (rg < 32) {
                const size_t idx = ((size_t)(b * NT + n)) * 32 + rg;
                qh[idx] = h; ql[idx] = l;
            } else if (rg < 64) {
                const size_t idx = ((size_t)(b * NT + n)) * 32 + (rg - 32);
                kh[idx] = h; kl[idx] = l;
            } else {
                pvw[((size_t)b * CC + (rg - 64)) * NT + n] = f2b(val);
            }
        }
    }
}

// ---------------------------------------------------------------------------
// K2 (fused) v2: sa + out. Swapped QK^T (as R4). Phase-2 restructured:
//  - 32 periods of 2 k-steps (128 k-cols) between barriers (was 64 barriers)
//  - TRIPLE-buffered LDS tile [3][32 m][128 k] (XOR swizzle both sides):
//    A(p) writes buf[(p+1)%3]; C(p) reads buf[p%3]; one barrier per period
//    is race-free (write target of p+1 != read buf of p; b(p) orders rotation)
//  - full-slack reg prefetch: pa frags reloaded right after last use in C(p)
//    (used C(p+1)); QK operands reloaded right after use in A(p)
//  - T5 setprio(1) around the 16-MFMA PV cluster
// ---------------------------------------------------------------------------
#define MFMA_BF16(A, B, C) __builtin_amdgcn_mfma_f32_16x16x32_bf16(A, B, C, 0, 0, 0)

__global__ __launch_bounds__(512, 4) void ksaout(
    const u16* __restrict__ qh, const u16* __restrict__ ql,
    const u16* __restrict__ kh, const u16* __restrict__ kl,
    const float* __restrict__ valid, const u16* __restrict__ pvw,
    const float* __restrict__ x, const float* __restrict__ gamma,
    float* __restrict__ sa, float* __restrict__ outp)
{
    __shared__ __align__(16) u16 lB[3][32][128];  // 3 x 8 KB, swizzled
    __shared__ float sred[2][4][16];              // [rg][cq][row]
    const int b    = blockIdx.y;
    const int m0   = blockIdx.x * 32;
    const int t    = threadIdx.x;
    const int lane = t & 63;
    const int wv   = t >> 6;
    const int quad = lane >> 4, l16 = lane & 15;
    const int rg   = wv >> 2, cq = wv & 3;
    const int swz  = (l16 & 7) << 4;

    // Q fragments (B-operand of swapped QK^T), rows m0+rg*16+l16
    const size_t qbase = ((size_t)(b * NT + m0 + rg * 16 + l16)) * 32 + quad * 8;
    const short8 aqh = *(const short8*)(qh + qbase);
    const short8 aql = *(const short8*)(ql + qbase);
    // K fragment base (A-operand): key row ct*16+l16, channel chunk quad*8
    const size_t kbase = (size_t)b * NT * 32 + (size_t)l16 * 32 + quad * 8;
    const float* vbase = valid + (size_t)b * NT;
    const f32x4 zero = {0.f, 0.f, 0.f, 0.f};

    // ---------------- phase 1: row sums ----------------
    float sacc = 0.f;
    {
        short8 nbh = *(const short8*)(kh + kbase + (size_t)(cq * 64) * 512);
        short8 nbl = *(const short8*)(kl + kbase + (size_t)(cq * 64) * 512);
        f32x4  nv4 = *(const f32x4*)(vbase + (cq * 64) * 16 + quad * 4);
        for (int s = 0; s < 64; ++s) {
            short8 bh = nbh, bl = nbl;
            f32x4 v4 = nv4;
            if (s + 1 < 64) {
                const int ct = cq * 64 + s + 1;
                nbh = *(const short8*)(kh + kbase + (size_t)ct * 512);
                nbl = *(const short8*)(kl + kbase + (size_t)ct * 512);
                nv4 = *(const f32x4*)(vbase + ct * 16 + quad * 4);
            }
            f32x4 d = MFMA_BF16(bh, aqh, zero);
            d = MFMA_BF16(bh, aql, d);
            d = MFMA_BF16(bl, aqh, d);
            #pragma unroll
            for (int i = 0; i < 4; ++i)
                sacc += v4[i] * exp2f(fminf(d[i], 60.f) * L2E);
        }
    }
    sacc += __shfl_xor(sacc, 16, 64);
    sacc += __shfl_xor(sacc, 32, 64);
    if (lane < 16) sred[rg][cq][l16] = sacc;
    __syncthreads();
    const float inv = 1.0f / (sred[rg][0][l16] + sred[rg][1][l16] +
                              sred[rg][2][l16] + sred[rg][3][l16]);

    // ---------------- phase 2: emit sa + PV accumulate ----------------
    const u16* pva = pvw + ((size_t)(b * CC + wv * 32 + l16)) * NT + quad * 8;
    float* sap = sa + ((size_t)(b * NT + m0 + rg * 16 + l16)) * NT;
    char* lbB = (char*)&lB[0][0][0];
    const int lwoff = (rg * 16 + l16) * 256 + ((cq * 32 + quad * 8) ^ swz);

    f32x4 acc00 = {0,0,0,0}, acc01 = {0,0,0,0}, acc10 = {0,0,0,0}, acc11 = {0,0,0,0};

#define LOADQK(S, BH, BL, VV)                                                  \
    { int ct_ = (S) * 4 + cq; if (ct_ > 255) ct_ = 255;                        \
      BH = *(const short8*)(kh + kbase + (size_t)ct_ * 512);                   \
      BL = *(const short8*)(kl + kbase + (size_t)ct_ * 512);                   \
      VV = *(const f32x4*)(vbase + ct_ * 16 + quad * 4); }

#define ASTEP(S, J, BUF, BH, BL, VV)                                           \
    { f32x4 d = MFMA_BF16(BH, aqh, zero);                                      \
      d = MFMA_BF16(BH, aql, d);                                               \
      d = MFMA_BF16(BL, aqh, d);                                               \
      f32x4 val;                                                               \
      _Pragma("unroll")                                                        \
      for (int i = 0; i < 4; ++i)                                              \
          val[i] = VV[i] * exp2f(fminf(d[i], 60.f) * L2E) * inv;               \
      *(f32x4*)(sap + (size_t)(S) * 64 + cq * 16 + quad * 4) = val;            \
      u32x2 pk;                                                                \
      pk[0] = (u32)f2b(val[0]) | ((u32)f2b(val[1]) << 16);                     \
      pk[1] = (u32)f2b(val[2]) | ((u32)f2b(val[3]) << 16);                     \
      *(u32x2*)(lbB + (BUF) * 8192 + lwoff + (J) * 128) = pk; }

    short8 qbh0, qbl0, qbh1, qbl1;
    f32x4 qv0, qv1;
    short8 pac[8];

    // prologue: steps 0,1 -> buf0; QK for steps 2,3; pa for period 0
    LOADQK(0, qbh0, qbl0, qv0);
    LOADQK(1, qbh1, qbl1, qv1);
    ASTEP(0, 0, 0, qbh0, qbl0, qv0);
    ASTEP(1, 1, 0, qbh1, qbl1, qv1);
    LOADQK(2, qbh0, qbl0, qv0);
    LOADQK(3, qbh1, qbl1, qv1);
    #pragma unroll
    for (int k4 = 0; k4 < 4; ++k4) {
        pac[k4]     = *(const short8*)(pva + k4 * 32);
        pac[4 + k4] = *(const short8*)(pva + (size_t)16 * NT + k4 * 32);
    }
    asm volatile("s_waitcnt lgkmcnt(0)" ::: "memory");
    __builtin_amdgcn_sched_barrier(0);
    __builtin_amdgcn_s_barrier();
    __builtin_amdgcn_sched_barrier(0);

    for (int p = 0; p < 32; ++p) {
        const int rbuf = p % 3;
        if (p < 31) {
            const int wbuf = (p + 1) % 3;
            ASTEP(2 * p + 2, 0, wbuf, qbh0, qbl0, qv0);
            ASTEP(2 * p + 3, 1, wbuf, qbh1, qbl1, qv1);
            if (p < 30) {
                LOADQK(2 * p + 4, qbh0, qbl0, qv0);
                LOADQK(2 * p + 5, qbh1, qbl1, qv1);
            }
            asm volatile("s_waitcnt lgkmcnt(0)" ::: "memory");
            __builtin_amdgcn_sched_barrier(0);
            __builtin_amdgcn_s_barrier();
            __builtin_amdgcn_sched_barrier(0);
        }
        // C: 16 PV MFMAs vs staged 32x128 tile
        __builtin_amdgcn_s_setprio(1);
        #pragma unroll
        for (int k4 = 0; k4 < 4; ++k4) {
            const int kby = ((k4 * 64 + quad * 16) ^ swz);
            short8 b0 = *(const short8*)(lbB + rbuf * 8192 + l16 * 256 + kby);
            short8 b1 = *(const short8*)(lbB + rbuf * 8192 + (16 + l16) * 256 + kby);
            acc00 = MFMA_BF16(pac[k4], b0, acc00);
            acc01 = MFMA_BF16(pac[k4], b1, acc01);
            acc10 = MFMA_BF16(pac[4 + k4], b0, acc10);
            acc11 = MFMA_BF16(pac[4 + k4], b1, acc11);
        }
        __builtin_amdgcn_s_setprio(0);
        if (p < 31) {   // reload pa for period p+1 (right after last use)
            #pragma unroll
            for (int k4 = 0; k4 < 4; ++k4) {
                pac[k4]     = *(const short8*)(pva + (size_t)(p + 1) * 128 + k4 * 32);
                pac[4 + k4] = *(const short8*)(pva + (size_t)(p + 1) * 128
                                               + (size_t)16 * NT + k4 * 32);
            }
        }
    }
#undef LOADQK
#undef ASTEP

    // epilogue: D row = c (A rows), col = m (B cols)
    const float g = gamma[0];
    #pragma unroll
    for (int ai = 0; ai < 2; ++ai) {
        #pragma unroll
        for (int bi = 0; bi < 2; ++bi) {
            f32x4 acc = (ai == 0) ? ((bi == 0) ? acc00 : acc01)
                                  : ((bi == 0) ? acc10 : acc11);
            #pragma unroll
            for (int i = 0; i < 4; ++i) {
                const int c = wv * 32 + ai * 16 + quad * 4 + i;
                const int m = m0 + bi * 16 + l16;
                const size_t idx = ((size_t)(b * CC + c)) * NT + m;
                outp[idx] = g * acc[i] + x[idx];
            }
        }
    }
}

extern "C" void kernel_launch(void* const* d_in, const int* in_sizes, int n_in,
                              void* d_out, int out_size, void* d_ws, size_t ws_size,
                              hipStream_t stream)
{
    const float* x     = (const float*)d_in[0];
    const float* valid = (const float*)d_in[1];
    const float* Wq    = (const float*)d_in[2];
    const float* bq    = (const float*)d_in[3];
    const float* Wk    = (const float*)d_in[4];
    const float* bk    = (const float*)d_in[5];
    const float* Wv    = (const float*)d_in[6];
    const float* bv    = (const float*)d_in[7];
    const float* gamma = (const float*)d_in[8];

    float* outp = (float*)d_out;
    float* sa   = outp + (size_t)BB * CC * NT;      // output chunk 1 [B][N][N] fp32

    u16* qh  = (u16*)d_ws;                          // [B][N][32] bf16, 1 MB each
    u16* ql  = qh + (size_t)BB * NT * 32;
    u16* kh  = ql + (size_t)BB * NT * 32;
    u16* kl  = kh + (size_t)BB * NT * 32;
    u16* pvw = kl + (size_t)BB * NT * 32;           // [B][C][N] bf16, 8 MB

    kproj<<<dim3(5, 64, BB), 256, 0, stream>>>(x, Wq, bq, Wk, bk, Wv, bv,
                                               qh, ql, kh, kl, pvw);
    ksaout<<<dim3(128, BB), 512, 0, stream>>>(qh, ql, kh, kl, valid, pvw,
                                              x, gamma, sa, outp);
}